// Round 2
// baseline (918.627 us; speedup 1.0000x reference)
//
#include <hip/hip_runtime.h>
#include <hip/hip_bf16.h>

#define N_SPOKES 524288
#define DIM      128
#define DIM2     256
#define NB       128
#define NH       64
#define NKNN     4
#define BH       8192   // NB*NH

// d_out layout (all float32): [0,1048576) hub_features [8192][128]
//                             [1048576, +2097152) spokes_idx row
//                             [3145728, +2097152) hub ids row
#define OUT_HF   0
#define OUT_E0   1048576
#define OUT_E1   3145728

typedef __attribute__((ext_vector_type(8))) short  short8;
typedef __attribute__((ext_vector_type(4))) float  float4v;
typedef __attribute__((ext_vector_type(4))) unsigned short ushort4v;

__device__ inline unsigned short f2bf(float f) {
    __hip_bfloat16 h = __float2bfloat16(f);
    return *reinterpret_cast<unsigned short*>(&h);
}

// tanh-approx GELU via sigmoid identity: 0.5x(1+tanh(t)) = x*sigmoid(2t)
__device__ inline float gelu_f(float v) {
    float s = v * (1.0f + 0.044715f * v * v);            // v + 0.044715 v^3
    float e = __builtin_exp2f(-2.302118131f * s);        // exp(-1.5957691*s)
    return v / (1.0f + e);
}

// ---------- prep: W1 [128][256] f32 -> W1^T bf16 [n=256][k=128] ----------
__global__ void prep_w1t(const float* __restrict__ W1, unsigned short* __restrict__ w1t) {
    int idx = blockIdx.x * 256 + threadIdx.x;   // 32768 total
    if (idx < DIM * DIM2) {
        int n = idx >> 7;          // 0..255 output col
        int k = idx & 127;         // 0..127
        w1t[idx] = f2bf(W1[k * DIM2 + n]);
    }
}

// ---------- counts per hub ----------
__global__ void count_kernel(const int* __restrict__ hubidx, const int* __restrict__ batchidx,
                             int* __restrict__ cnt) {
    int i = blockIdx.x * 256 + threadIdx.x;
    if (i < N_SPOKES) {
        atomicAdd(&cnt[batchidx[i] * NH + hubidx[i]], 1);
    }
}

// ---------- fused: U = gelu(x@W1 + b1), scatter-add into hubsum ----------
// 4096 blocks x 256 thr. Block tile: M=128 spokes, N=256, K=128 one-shot.
// Wave tile: M=128 x N=64 (wave w owns cols 64w..64w+63). B frags in registers.
__launch_bounds__(256)
__global__ void ffn_scatter(const float* __restrict__ x,
                            const int* __restrict__ hubidx,
                            const int* __restrict__ batchidx,
                            const unsigned short* __restrict__ w1t,
                            const float* __restrict__ b1,
                            float* __restrict__ hubsum) {
    __shared__ unsigned short sA[128 * 136];   // bf16, row stride 136 (pad 8)
    __shared__ int sGid[128];

    const int tid  = threadIdx.x;
    const int lane = tid & 63;
    const int w    = tid >> 6;          // wave 0..3
    const int m0   = blockIdx.x * 128;
    const int c_lo = lane & 15;
    const int c_hi = lane >> 4;

    // stage A: 128x128 f32 -> bf16 LDS (coalesced float4 loads)
    const float4v* x4 = (const float4v*)(x + (size_t)m0 * DIM);
    #pragma unroll
    for (int it = 0; it < 16; ++it) {
        int f   = it * 256 + tid;       // 0..4095 float4 chunks
        int row = f >> 5;               // 32 chunks per row
        int c4  = f & 31;
        float4v v = x4[f];
        ushort4v u = { f2bf(v.x), f2bf(v.y), f2bf(v.z), f2bf(v.w) };
        *(ushort4v*)&sA[row * 136 + c4 * 4] = u;
    }
    if (tid < 128) sGid[tid] = batchidx[m0 + tid] * NH + hubidx[m0 + tid];

    // B fragments (wave-private cols) straight from w1t (L1-resident, 16 KB/wave)
    short8 bfr[4][4];
    #pragma unroll
    for (int n = 0; n < 4; ++n)
        #pragma unroll
        for (int k = 0; k < 4; ++k) {
            int col  = w * 64 + n * 16 + c_lo;
            int koff = k * 32 + c_hi * 8;
            bfr[n][k] = *(const short8*)(w1t + col * DIM + koff);
        }
    __syncthreads();

    float4v acc[8][4];
    #pragma unroll
    for (int m = 0; m < 8; ++m)
        #pragma unroll
        for (int n = 0; n < 4; ++n) acc[m][n] = (float4v){0.f, 0.f, 0.f, 0.f};

    #pragma unroll
    for (int k = 0; k < 4; ++k) {
        #pragma unroll
        for (int m = 0; m < 8; ++m) {
            short8 a = *(const short8*)&sA[(m * 16 + c_lo) * 136 + k * 32 + c_hi * 8];
            #pragma unroll
            for (int n = 0; n < 4; ++n)
                acc[m][n] = __builtin_amdgcn_mfma_f32_16x16x32_bf16(a, bfr[n][k], acc[m][n], 0, 0, 0);
        }
    }

    // epilogue: +b1, gelu, atomic scatter-add into hubsum[gid][col]
    #pragma unroll
    for (int m = 0; m < 8; ++m) {
        int rbase = m * 16 + c_hi * 4;
        #pragma unroll
        for (int n = 0; n < 4; ++n) {
            int col = w * 64 + n * 16 + c_lo;
            float bb = b1[col];
            float4v a4 = acc[m][n];
            #pragma unroll
            for (int r = 0; r < 4; ++r) {
                float g = gelu_f(a4[r] + bb);
                atomicAdd(&hubsum[(size_t)sGid[rbase + r] * DIM2 + col], g);
            }
        }
    }
}

// ---------- hub_features = (hubsum@W2 + cnt*b2) / max(cnt,1) ----------
// 512 blocks x 256 thr; block handles 16 hub rows (two groups of 8).
__global__ void hubfeat_kernel(const float* __restrict__ hubsum, const int* __restrict__ cnt,
                               const float* __restrict__ W2, const float* __restrict__ b2,
                               float* __restrict__ out) {
    int tid = threadIdx.x;
    int d   = tid & 127;
    int hh  = tid >> 7;                 // 0..1
    int h0  = blockIdx.x * 16 + hh * 8;

    float acc[8] = {0.f, 0.f, 0.f, 0.f, 0.f, 0.f, 0.f, 0.f};
    for (int k = 0; k < DIM2; ++k) {
        float wv = W2[k * DIM + d];
        #pragma unroll
        for (int j = 0; j < 8; ++j) acc[j] += hubsum[(h0 + j) * DIM2 + k] * wv;
    }
    float b2d = b2[d];
    #pragma unroll
    for (int j = 0; j < 8; ++j) {
        int h = h0 + j;
        float c = (float)cnt[h];
        out[OUT_HF + h * DIM + d] = (acc[j] + c * b2d) / fmaxf(c, 1.0f);
    }
}

// ---------- per-graph KNN (K=4 incl. self) ----------
__global__ void knn_kernel(const float* __restrict__ hf, int* __restrict__ knn) {
    __shared__ float s[64 * 129];     // pad 1 -> conflict-free j-varying reads
    __shared__ float d2[64 * 64];
    int g = blockIdx.x, tid = threadIdx.x;

    for (int i = tid; i < 64 * 128; i += 256) {
        int r = i >> 7, c = i & 127;
        s[r * 129 + c] = hf[OUT_HF + (g * 64 + r) * DIM + c];
    }
    __syncthreads();

    for (int p = tid; p < 4096; p += 256) {
        int i = p >> 6, j = p & 63;
        float a = 0.f;
        for (int k = 0; k < 128; ++k) {
            float dd = s[i * 129 + k] - s[j * 129 + k];
            a += dd * dd;
        }
        d2[p] = a;
    }
    __syncthreads();

    if (tid < 64) {
        float bv0 = 1e30f, bv1 = 1e30f, bv2 = 1e30f, bv3 = 1e30f;
        int   bi0 = 0,     bi1 = 0,     bi2 = 0,     bi3 = 0;
        for (int j = 0; j < 64; ++j) {
            float v = d2[tid * 64 + j];
            if (v < bv0)      { bv3=bv2; bi3=bi2; bv2=bv1; bi2=bi1; bv1=bv0; bi1=bi0; bv0=v; bi0=j; }
            else if (v < bv1) { bv3=bv2; bi3=bi2; bv2=bv1; bi2=bi1; bv1=v;   bi1=j; }
            else if (v < bv2) { bv3=bv2; bi3=bi2; bv2=v;   bi2=j; }
            else if (v < bv3) { bv3=v;   bi3=j; }
        }
        int base = (g * 64 + tid) * 4;
        knn[base + 0] = bi0; knn[base + 1] = bi1; knn[base + 2] = bi2; knn[base + 3] = bi3;
    }
}

// ---------- edges: row0 = repeat(arange(N),4), row1 = knn gather + b*64 ----------
__global__ void edges_kernel(const int* __restrict__ hubidx, const int* __restrict__ batchidx,
                             const int* __restrict__ knn, float* __restrict__ out) {
    int i = blockIdx.x * 256 + threadIdx.x;
    if (i < N_SPOKES) {
        int b = batchidx[i], h = hubidx[i];
        const int4* kp = (const int4*)&knn[(b * NH + h) * 4];
        int4 kn = *kp;
        float fi = (float)i;
        float4v o0 = { fi, fi, fi, fi };
        ((float4v*)(out + OUT_E0))[i] = o0;
        float base = (float)(b * NH);
        float4v o1 = { kn.x + base, kn.y + base, kn.z + base, kn.w + base };
        ((float4v*)(out + OUT_E1))[i] = o1;
    }
}

extern "C" void kernel_launch(void* const* d_in, const int* in_sizes, int n_in,
                              void* d_out, int out_size, void* d_ws, size_t ws_size,
                              hipStream_t stream) {
    const float* x        = (const float*)d_in[0];
    const int*   hubidx   = (const int*)d_in[1];
    const int*   batchidx = (const int*)d_in[2];
    const float* W1       = (const float*)d_in[3];
    const float* b1       = (const float*)d_in[4];
    const float* W2       = (const float*)d_in[5];
    const float* b2       = (const float*)d_in[6];
    float* out = (float*)d_out;
    char*  ws  = (char*)d_ws;

    float*          hubsum = (float*)ws;                        // 8192*256*4 = 8388608 B
    int*            cnt    = (int*)(ws + 8388608);              // 32768 B
    unsigned short* w1t    = (unsigned short*)(ws + 8421376);   // 65536 B
    int*            knn    = (int*)(ws + 8486912);              // 131072 B

    (void)hipMemsetAsync(ws, 0, 8421376, stream);               // zero hubsum + cnt

    prep_w1t   <<<128,  256, 0, stream>>>(W1, w1t);
    count_kernel<<<2048, 256, 0, stream>>>(hubidx, batchidx, cnt);
    ffn_scatter<<<4096, 256, 0, stream>>>(x, hubidx, batchidx, w1t, b1, hubsum);
    hubfeat_kernel<<<512, 256, 0, stream>>>(hubsum, cnt, W2, b2, out);
    knn_kernel <<<NB,   256, 0, stream>>>(out, knn);
    edges_kernel<<<2048, 256, 0, stream>>>(hubidx, batchidx, knn, out);
}